// Round 5
// baseline (507.064 us; speedup 1.0000x reference)
//
#include <hip/hip_runtime.h>
#include <hip/hip_bf16.h>
#include <math.h>

typedef __attribute__((ext_vector_type(8))) short bf16x8;
typedef __attribute__((ext_vector_type(4))) float f32x4;

__device__ __forceinline__ unsigned short f2bf(float f) {
    unsigned int u = __float_as_uint(f);
    u = (u + 0x7fff + ((u >> 16) & 1)) >> 16;   // RNE
    return (unsigned short)u;
}

__device__ __forceinline__ void async_copy16(const unsigned short* g, unsigned short* l) {
    __builtin_amdgcn_global_load_lds(
        (const __attribute__((address_space(1))) unsigned int*)g,
        (__attribute__((address_space(3))) unsigned int*)l,
        16, 0, 0);
}

// ---------------- fp32 -> bf16 conversion (vectorized) ----------------
__global__ __launch_bounds__(256) void f32_to_bf16_kernel(
    const float* __restrict__ in, unsigned short* __restrict__ out, int n4)
{
    const int i = blockIdx.x * 256 + threadIdx.x;
    if (i >= n4) return;
    const float4 v = ((const float4*)in)[i];
    ushort4 o;
    o.x = f2bf(v.x); o.y = f2bf(v.y); o.z = f2bf(v.z); o.w = f2bf(v.w);
    ((ushort4*)out)[i] = o;
}

// ---------------- bf16 MFMA GEMM: C[m][n] = sum_k A[m][k] * W[n][k] ----------------
template <int BMT, int BNT>
__global__ __launch_bounds__(256) void gemm_bf16_nt(
    const unsigned short* __restrict__ A,
    const unsigned short* __restrict__ W,
    float* __restrict__ C, int M, int N, int K)
{
    constexpr int FM = BMT / 32;
    constexpr int FN = BNT / 32;
    constexpr int ACH = BMT / 16;
    constexpr int BCH = BNT / 16;

    __shared__ unsigned short Alds[BMT][32];
    __shared__ unsigned short Blds[BNT][32];

    const int tid  = threadIdx.x;
    const int lane = tid & 63;
    const int wave = tid >> 6;
    const int wr = wave >> 1, wc = wave & 1;
    const int m0 = blockIdx.y * BMT;
    const int n0 = blockIdx.x * BNT;

    const int srow = lane >> 2;
    const int scol = (lane & 3) * 8;

    f32x4 acc[FM][FN];
#pragma unroll
    for (int i = 0; i < FM; ++i)
#pragma unroll
        for (int j = 0; j < FN; ++j) acc[i][j] = (f32x4){0.f, 0.f, 0.f, 0.f};

    const int lrow = lane & 15;
    const int lk16 = (lane >> 4) * 8;

    for (int k0 = 0; k0 < K; k0 += 32) {
#pragma unroll
        for (int c = wave; c < ACH; c += 4) {
            const unsigned short* src = A + (size_t)(m0 + c * 16 + srow) * K + k0 + scol;
            async_copy16(src, &Alds[c * 16][0]);
        }
#pragma unroll
        for (int c = wave; c < BCH; c += 4) {
            const unsigned short* src = W + (size_t)(n0 + c * 16 + srow) * K + k0 + scol;
            async_copy16(src, &Blds[c * 16][0]);
        }
        __syncthreads();

        bf16x8 af[FM], bfr[FN];
#pragma unroll
        for (int fm = 0; fm < FM; ++fm)
            af[fm] = *(const bf16x8*)&Alds[wr * (BMT / 2) + fm * 16 + lrow][lk16];
#pragma unroll
        for (int fn = 0; fn < FN; ++fn)
            bfr[fn] = *(const bf16x8*)&Blds[wc * (BNT / 2) + fn * 16 + lrow][lk16];
#pragma unroll
        for (int fm = 0; fm < FM; ++fm)
#pragma unroll
            for (int fn = 0; fn < FN; ++fn)
                acc[fm][fn] = __builtin_amdgcn_mfma_f32_16x16x32_bf16(
                    af[fm], bfr[fn], acc[fm][fn], 0, 0, 0);
        __syncthreads();
    }

    const int lq = lane >> 4;
#pragma unroll
    for (int fm = 0; fm < FM; ++fm) {
#pragma unroll
        for (int fn = 0; fn < FN; ++fn) {
#pragma unroll
            for (int r = 0; r < 4; ++r) {
                const int m = m0 + wr * (BMT / 2) + fm * 16 + lq * 4 + r;
                const int n = n0 + wc * (BNT / 2) + fn * 16 + lrow;
                C[(size_t)m * N + n] = acc[fm][fn][r];
            }
        }
    }
}

// ---------------- K3: split-K bf16 MFMA, N=96 ----------------
__global__ __launch_bounds__(256) void gemm_bf16_k3(
    const unsigned short* __restrict__ A,
    const unsigned short* __restrict__ W,
    float* __restrict__ P)
{
    __shared__ unsigned short Alds[128][32];
    __shared__ unsigned short Blds[96][32];

    const int tid  = threadIdx.x;
    const int lane = tid & 63;
    const int wave = tid >> 6;
    const int wr = wave >> 1, wc = wave & 1;
    const int ks = blockIdx.x;
    const int m0 = blockIdx.y * 128;
    const int kbase = ks * 128;

    const int srow = lane >> 2;
    const int scol = (lane & 3) * 8;
    const int lrow = lane & 15;
    const int lk16 = (lane >> 4) * 8;

    f32x4 acc[4][3];
#pragma unroll
    for (int i = 0; i < 4; ++i)
#pragma unroll
        for (int j = 0; j < 3; ++j) acc[i][j] = (f32x4){0.f, 0.f, 0.f, 0.f};

    for (int kk = 0; kk < 4; ++kk) {
        const int k0 = kbase + kk * 32;
#pragma unroll
        for (int c = wave; c < 8; c += 4)
            async_copy16(A + (size_t)(m0 + c * 16 + srow) * 2048 + k0 + scol, &Alds[c * 16][0]);
#pragma unroll
        for (int c = wave; c < 6; c += 4)
            async_copy16(W + (size_t)(c * 16 + srow) * 2048 + k0 + scol, &Blds[c * 16][0]);
        __syncthreads();

        bf16x8 af[4], bfr[3];
#pragma unroll
        for (int fm = 0; fm < 4; ++fm)
            af[fm] = *(const bf16x8*)&Alds[wr * 64 + fm * 16 + lrow][lk16];
#pragma unroll
        for (int fn = 0; fn < 3; ++fn)
            bfr[fn] = *(const bf16x8*)&Blds[wc * 48 + fn * 16 + lrow][lk16];
#pragma unroll
        for (int fm = 0; fm < 4; ++fm)
#pragma unroll
            for (int fn = 0; fn < 3; ++fn)
                acc[fm][fn] = __builtin_amdgcn_mfma_f32_16x16x32_bf16(
                    af[fm], bfr[fn], acc[fm][fn], 0, 0, 0);
        __syncthreads();
    }

    const int lq = lane >> 4;
    float* Pks = P + (size_t)ks * 2048 * 96;
#pragma unroll
    for (int fm = 0; fm < 4; ++fm) {
#pragma unroll
        for (int fn = 0; fn < 3; ++fn) {
#pragma unroll
            for (int r = 0; r < 4; ++r) {
                const int m = m0 + wr * 64 + fm * 16 + lq * 4 + r;
                const int n = wc * 48 + fn * 16 + lrow;
                Pks[(size_t)m * 96 + n] = acc[fm][fn][r];
            }
        }
    }
}

// reduce 16 partials -> proj (2048 x 96), float4-vectorized
__global__ __launch_bounds__(256) void k3_reduce_kernel(
    const float* __restrict__ P, float* __restrict__ proj)
{
    const int i = blockIdx.x * 256 + threadIdx.x;   // 0..49151 (2048*96/4)
    if (i >= 49152) return;
    float4 s = make_float4(0.f, 0.f, 0.f, 0.f);
#pragma unroll
    for (int ks = 0; ks < 16; ++ks) {
        const float4 v = ((const float4*)P)[(size_t)ks * 49152 + i];
        s.x += v.x; s.y += v.y; s.z += v.z; s.w += v.w;
    }
    ((float4*)proj)[i] = s;
}

// ---------------- K4: delta = softplus(proj[:, :64] @ dt_proj_w^T + b) ----------------
__global__ __launch_bounds__(256) void delta_gemm_kernel(
    const float* __restrict__ A,    // proj, lda=96
    const float* __restrict__ W,    // dt_proj_w, ldw=64
    const float* __restrict__ bias, // dt_proj_b
    float* __restrict__ C)          // delta, ldc=2048
{
    __shared__ float As[64][64];
    __shared__ float Bs[64][64];

    const int tid = threadIdx.x;
    const int m0 = blockIdx.y * 64;
    const int n0 = blockIdx.x * 64;

    {
        const int k4 = tid & 15;
        const int r0 = tid >> 4;      // 0..15
#pragma unroll
        for (int p = 0; p < 4; ++p) {
            const int row = p * 16 + r0;
            const int sw  = k4 ^ (row & 7) ^ (row >> 3);
            *(float4*)&As[row][sw * 4] =
                *(const float4*)(A + (size_t)(m0 + row) * 96 + k4 * 4);
            *(float4*)&Bs[row][sw * 4] =
                *(const float4*)(W + (size_t)(n0 + row) * 64 + k4 * 4);
        }
    }
    __syncthreads();

    const int tx = tid & 15;     // n-group (4 cols)
    const int ty = tid >> 4;     // m-group (4 rows)

    float acc[4][4];
#pragma unroll
    for (int i = 0; i < 4; ++i)
#pragma unroll
        for (int j = 0; j < 4; ++j) acc[i][j] = 0.f;

#pragma unroll 4
    for (int c = 0; c < 16; ++c) {   // 16 chunks of 4 k
        float4 a[4], b[4];
#pragma unroll
        for (int i = 0; i < 4; ++i) {
            const int r = ty * 4 + i;
            a[i] = *(const float4*)&As[r][(c ^ (r & 7) ^ (r >> 3)) * 4];
        }
#pragma unroll
        for (int j = 0; j < 4; ++j) {
            const int r = tx * 4 + j;
            b[j] = *(const float4*)&Bs[r][(c ^ (r & 7) ^ (r >> 3)) * 4];
        }
#pragma unroll
        for (int i = 0; i < 4; ++i)
#pragma unroll
            for (int j = 0; j < 4; ++j) {
                acc[i][j] = fmaf(a[i].x, b[j].x, acc[i][j]);
                acc[i][j] = fmaf(a[i].y, b[j].y, acc[i][j]);
                acc[i][j] = fmaf(a[i].z, b[j].z, acc[i][j]);
                acc[i][j] = fmaf(a[i].w, b[j].w, acc[i][j]);
            }
    }

    const float4 bv = *(const float4*)(bias + n0 + tx * 4);
#pragma unroll
    for (int i = 0; i < 4; ++i) {
        const int m = m0 + ty * 4 + i;
        float v[4];
        v[0] = acc[i][0] + bv.x; v[1] = acc[i][1] + bv.y;
        v[2] = acc[i][2] + bv.z; v[3] = acc[i][3] + bv.w;
        float4 o;
        o.x = (v[0] > 20.f) ? v[0] : __logf(1.f + __expf(v[0]));
        o.y = (v[1] > 20.f) ? v[1] : __logf(1.f + __expf(v[1]));
        o.z = (v[2] > 20.f) ? v[2] : __logf(1.f + __expf(v[2]));
        o.w = (v[3] > 20.f) ? v[3] : __logf(1.f + __expf(v[3]));
        *(float4*)(C + (size_t)m * 2048 + n0 + tx * 4) = o;
    }
}

// causal depthwise conv (width 4) + bias + SiLU; writes fp32 + bf16
__global__ __launch_bounds__(256) void conv_silu_kernel(
    const float* __restrict__ xz, const float* __restrict__ cw,
    const float* __restrict__ cb, float* __restrict__ xs,
    unsigned short* __restrict__ xs_bf)
{
    const int idx = blockIdx.x * 256 + threadIdx.x;
    if (idx >= 2 * 1024 * 2048) return;
    const int d = idx & 2047;
    const int t = (idx >> 11) & 1023;
    const int b = idx >> 21;

    const float* col = xz + (size_t)b * 1024 * 4096 + d;
    const float4 w = *(const float4*)(cw + d * 4);
    float acc = cb[d];
    const int tb = t - 3;
    const float s0 = (tb + 0 >= 0) ? col[(size_t)(tb + 0) * 4096] : 0.f;
    const float s1 = (tb + 1 >= 0) ? col[(size_t)(tb + 1) * 4096] : 0.f;
    const float s2 = (tb + 2 >= 0) ? col[(size_t)(tb + 2) * 4096] : 0.f;
    const float s3 = col[(size_t)t * 4096];
    acc += w.x * s0 + w.y * s1 + w.z * s2 + w.w * s3;
    const float sig = 1.f / (1.f + __expf(-acc));
    const float val = acc * sig;
    xs[idx] = val;
    xs_bf[idx] = f2bf(val);
}

// ---------------- chunked selective scan ----------------
// n=16 per thread, 1024 blocks (d = db*256+tid). Per 8-t half-chunk: register
// burst-preload of dt/xs(/z). B/C rows via ds_read_b128 with EXPLICIT .x/.y/.z/.w
// component access (no pointer into local arrays -> no alloca/scratch; rule #20).
#define SCAN_STEP(J, BC, CC)                                                  \
    {                                                                          \
        const float dA2 = dt_v * A2[J];                                        \
        const float a = __builtin_amdgcn_exp2f(dA2);                           \
        const float bb = (fabsf(dA2) < 0.0144269504f) ? dt_v                   \
                                                      : (a - 1.f) * invA[J];   \
        h[J] = fmaf(a, h[J], bb * (BC * xs_v));                                \
        if (PHASE == 1) Pacc[J] *= a;                                          \
        else ysum = fmaf(h[J], CC, ysum);                                      \
    }

template <int PHASE>
__global__ __launch_bounds__(256, 4) void scan_phase_kernel(
    const float* __restrict__ delta, const float* __restrict__ xs,
    const float* __restrict__ xz, const float* __restrict__ proj,
    const float* __restrict__ A_log, const float* __restrict__ Dp,
    float* __restrict__ Pbuf, float* __restrict__ hcbuf,
    unsigned short* __restrict__ ybf)
{
    const int tid = threadIdx.x;
    const int cb = blockIdx.x;
    const int chunk = cb & 63;
    const int db = (cb >> 6) & 7;
    const int b = cb >> 9;
    const int d = db * 256 + tid;
    const int t0 = chunk * 16;

    __shared__ float Bs[16][16];
    __shared__ float Cs[16][16];
    {
        const int tt = tid >> 4, nn = tid & 15;
        Bs[tt][nn] = proj[((size_t)b * 1024 + t0 + tt) * 96 + 64 + nn];
        if (PHASE == 3)
            Cs[tt][nn] = proj[((size_t)b * 1024 + t0 + tt) * 96 + 80 + nn];
    }

    // A2 = A * log2e (for exp2); invA = 1/A
    float A2[16], invA[16], h[16], Pacc[16];
#pragma unroll
    for (int n4 = 0; n4 < 4; ++n4) {
        const float4 al = *(const float4*)(A_log + d * 16 + n4 * 4);
        const float a0 = -__expf(al.x);
        const float a1 = -__expf(al.y);
        const float a2 = -__expf(al.z);
        const float a3 = -__expf(al.w);
        A2[n4 * 4 + 0] = a0 * 1.44269504088896f; invA[n4 * 4 + 0] = 1.f / a0;
        A2[n4 * 4 + 1] = a1 * 1.44269504088896f; invA[n4 * 4 + 1] = 1.f / a1;
        A2[n4 * 4 + 2] = a2 * 1.44269504088896f; invA[n4 * 4 + 2] = 1.f / a2;
        A2[n4 * 4 + 3] = a3 * 1.44269504088896f; invA[n4 * 4 + 3] = 1.f / a3;
    }
#pragma unroll
    for (int j = 0; j < 16; ++j) Pacc[j] = 1.f;
    if (PHASE == 1) {
#pragma unroll
        for (int j = 0; j < 16; ++j) h[j] = 0.f;
    } else {
#pragma unroll
        for (int j = 0; j < 16; ++j)
            h[j] = hcbuf[(((size_t)b * 64 + chunk) * 16 + j) * 2048 + d];
    }
    const float Dd = Dp[d];

    const float* dptr = delta + ((size_t)b * 1024 + t0) * 2048 + d;
    const float* xptr = xs + ((size_t)b * 1024 + t0) * 2048 + d;
    const float* zptr = xz + ((size_t)b * 1024 + t0) * 4096 + 2048 + d;
    unsigned short* yptr = ybf + ((size_t)b * 1024 + t0) * 2048 + d;

    __syncthreads();

#pragma unroll
    for (int half = 0; half < 2; ++half) {
        // burst-preload 8 t-steps of dt/xs (and z) into registers
        float dtv[8], xsv[8], zv[8];
#pragma unroll
        for (int q = 0; q < 8; ++q) {
            const int t = half * 8 + q;
            dtv[q] = dptr[(size_t)t * 2048];
            xsv[q] = xptr[(size_t)t * 2048];
            if (PHASE == 3) zv[q] = zptr[(size_t)t * 4096];
        }
#pragma unroll
        for (int q = 0; q < 8; ++q) {
            const int t = half * 8 + q;
            const float dt_v = dtv[q];
            const float xs_v = xsv[q];
            float ysum = 0.f;
#pragma unroll
            for (int n4 = 0; n4 < 4; ++n4) {
                const float4 Bv = *(const float4*)&Bs[t][n4 * 4];   // broadcast b128
                float4 Cv = make_float4(0.f, 0.f, 0.f, 0.f);
                if (PHASE == 3) Cv = *(const float4*)&Cs[t][n4 * 4];
                SCAN_STEP(n4 * 4 + 0, Bv.x, Cv.x)
                SCAN_STEP(n4 * 4 + 1, Bv.y, Cv.y)
                SCAN_STEP(n4 * 4 + 2, Bv.z, Cv.z)
                SCAN_STEP(n4 * 4 + 3, Bv.w, Cv.w)
            }
            if (PHASE == 3) {
                const float z_v = zv[q];
                const float yv = ysum + Dd * xs_v;
                const float sig = 1.f / (1.f + __expf(-z_v));
                yptr[(size_t)t * 2048] = f2bf(yv * (z_v * sig));
            }
        }
    }
    if (PHASE == 1) {
#pragma unroll
        for (int j = 0; j < 16; ++j) {
            const size_t idx = (((size_t)b * 64 + chunk) * 16 + j) * 2048 + d;
            Pbuf[idx] = Pacc[j];
            hcbuf[idx] = h[j];
        }
    }
}

__global__ __launch_bounds__(256) void scan_combine_kernel(
    const float* __restrict__ Pbuf, float* __restrict__ hcbuf)
{
    const int gid = blockIdx.x * 256 + threadIdx.x;
    const int d = gid & 2047;
    const int n = (gid >> 11) & 15;
    const int b = gid >> 15;

    const size_t base = (((size_t)b * 64) * 16 + n) * 2048 + d;
    const size_t cstride = (size_t)16 * 2048;

    float H = 0.f;
    float P = Pbuf[base], hl = hcbuf[base];
    for (int c = 0; c < 64; ++c) {
        float nP = 0.f, nhl = 0.f;
        if (c + 1 < 64) {
            nP  = Pbuf[base + (size_t)(c + 1) * cstride];
            nhl = hcbuf[base + (size_t)(c + 1) * cstride];
        }
        hcbuf[base + (size_t)c * cstride] = H;
        H = fmaf(P, H, hl);
        P = nP; hl = nhl;
    }
}

extern "C" void kernel_launch(void* const* d_in, const int* in_sizes, int n_in,
                              void* d_out, int out_size, void* d_ws, size_t ws_size,
                              hipStream_t stream) {
    const float* x         = (const float*)d_in[0];
    const float* in_proj_w = (const float*)d_in[1];
    const float* conv_w    = (const float*)d_in[2];
    const float* conv_b    = (const float*)d_in[3];
    const float* x_proj_w  = (const float*)d_in[4];
    const float* dt_proj_w = (const float*)d_in[5];
    const float* dt_proj_b = (const float*)d_in[6];
    const float* A_log     = (const float*)d_in[7];
    const float* Dp        = (const float*)d_in[8];
    const float* out_proj_w= (const float*)d_in[9];
    float* out = (float*)d_out;

    float* ws    = (float*)d_ws;
    float* xz    = ws;                              // (2048,4096) 32 MB
    float* xs    = ws + 8388608;                    // (2048,2048) 16 MB
    float* delta = ws + 12582912;                   // (2048,2048) 16 MB
    float* Pbuf  = ws + 16777216;                   // 16 MB
    float* proj  = ws + 20971520;                   // (2048,96)
    float* hcbuf = ws + 21168128;                   // 16 MB

    // bf16 staging / partial buffers in dead regions:
    unsigned short* x_bf   = (unsigned short*)(ws + 12582912); // delta region (dead until K4)
    unsigned short* w1_bf  = (unsigned short*)(ws + 13631488); // delta region, ends at 15728640
    float*          part3  = ws + 12582912;                    // [16][2048][96] fp32, K3 partials (after K1)
    unsigned short* xw_bf  = (unsigned short*)(ws + 15728640); // 96x2048 bf16
    unsigned short* xs_bf  = (unsigned short*)(ws + 16777216); // Pbuf region (dead until scan ph1)
    unsigned short* ybf    = (unsigned short*)(ws + 16777216); // over Pbuf (dead after combine)
    unsigned short* wout_bf= (unsigned short*)ws;              // xz region (dead after phase 3)

    // conversions
    f32_to_bf16_kernel<<<2048, 256, 0, stream>>>(x, x_bf, 524288);
    f32_to_bf16_kernel<<<4096, 256, 0, stream>>>(in_proj_w, w1_bf, 1048576);
    f32_to_bf16_kernel<<<192, 256, 0, stream>>>(x_proj_w, xw_bf, 49152);

    // K1: xz = x @ in_proj_w^T   (M=2048, N=4096, K=1024) — bf16 MFMA
    gemm_bf16_nt<128, 128><<<dim3(4096 / 128, 2048 / 128), 256, 0, stream>>>(
        x_bf, w1_bf, xz, 2048, 4096, 1024);

    // K2: causal conv + bias + silu -> xs (fp32) + xs_bf (bf16)
    conv_silu_kernel<<<(2 * 1024 * 2048) / 256, 256, 0, stream>>>(xz, conv_w, conv_b, xs, xs_bf);

    // K3: split-K bf16 MFMA -> partials -> reduce into proj
    gemm_bf16_k3<<<dim3(16, 16), 256, 0, stream>>>(xs_bf, xw_bf, part3);
    k3_reduce_kernel<<<192, 256, 0, stream>>>(part3, proj);

    // K4: delta = softplus(proj[:, :64] @ dt_proj_w^T + dt_proj_b) — fp32, 64x64 tiles
    delta_gemm_kernel<<<dim3(2048 / 64, 2048 / 64), 256, 0, stream>>>(
        proj, dt_proj_w, dt_proj_b, delta);

    // K5: chunked selective scan -> ybf (bf16); 1024 blocks, n=16/thread, reg-preload
    scan_phase_kernel<1><<<1024, 256, 0, stream>>>(
        delta, xs, xz, proj, A_log, Dp, Pbuf, hcbuf, ybf);
    scan_combine_kernel<<<256, 256, 0, stream>>>(Pbuf, hcbuf);
    scan_phase_kernel<3><<<1024, 256, 0, stream>>>(
        delta, xs, xz, proj, A_log, Dp, Pbuf, hcbuf, ybf);

    // convert out_proj_w into xz region (xz dead after phase 3)
    f32_to_bf16_kernel<<<2048, 256, 0, stream>>>(out_proj_w, wout_bf, 524288);

    // K7: out = y @ out_proj_w^T  (M=2048, N=1024, K=2048) — bf16 MFMA
    gemm_bf16_nt<64, 128><<<dim3(1024 / 128, 2048 / 64), 256, 0, stream>>>(
        ybf, wout_bf, out, 2048, 1024, 2048);
}

// Round 6
// 172.639 us; speedup vs baseline: 2.9371x; 2.9371x over previous
//
#include <hip/hip_runtime.h>
#include <hip/hip_bf16.h>
#include <math.h>

typedef __attribute__((ext_vector_type(8))) short bf16x8;
typedef __attribute__((ext_vector_type(4))) float f32x4;

__device__ __forceinline__ unsigned short f2bf(float f) {
    unsigned int u = __float_as_uint(f);
    u = (u + 0x7fff + ((u >> 16) & 1)) >> 16;   // RNE
    return (unsigned short)u;
}

__device__ __forceinline__ void async_copy16(const unsigned short* g, unsigned short* l) {
    __builtin_amdgcn_global_load_lds(
        (const __attribute__((address_space(1))) unsigned int*)g,
        (__attribute__((address_space(3))) unsigned int*)l,
        16, 0, 0);
}

// ---------------- fp32 -> bf16 conversion (vectorized) ----------------
__global__ __launch_bounds__(256) void f32_to_bf16_kernel(
    const float* __restrict__ in, unsigned short* __restrict__ out, int n4)
{
    const int i = blockIdx.x * 256 + threadIdx.x;
    if (i >= n4) return;
    const float4 v = ((const float4*)in)[i];
    ushort4 o;
    o.x = f2bf(v.x); o.y = f2bf(v.y); o.z = f2bf(v.z); o.w = f2bf(v.w);
    ((ushort4*)out)[i] = o;
}

// ---------------- bf16 MFMA GEMM: C[m][n] = sum_k A[m][k] * W[n][k] ----------------
template <int BMT, int BNT>
__global__ __launch_bounds__(256) void gemm_bf16_nt(
    const unsigned short* __restrict__ A,
    const unsigned short* __restrict__ W,
    float* __restrict__ C, int M, int N, int K)
{
    constexpr int FM = BMT / 32;
    constexpr int FN = BNT / 32;
    constexpr int ACH = BMT / 16;
    constexpr int BCH = BNT / 16;

    __shared__ unsigned short Alds[BMT][32];
    __shared__ unsigned short Blds[BNT][32];

    const int tid  = threadIdx.x;
    const int lane = tid & 63;
    const int wave = tid >> 6;
    const int wr = wave >> 1, wc = wave & 1;
    const int m0 = blockIdx.y * BMT;
    const int n0 = blockIdx.x * BNT;

    const int srow = lane >> 2;
    const int scol = (lane & 3) * 8;

    f32x4 acc[FM][FN];
#pragma unroll
    for (int i = 0; i < FM; ++i)
#pragma unroll
        for (int j = 0; j < FN; ++j) acc[i][j] = (f32x4){0.f, 0.f, 0.f, 0.f};

    const int lrow = lane & 15;
    const int lk16 = (lane >> 4) * 8;

    for (int k0 = 0; k0 < K; k0 += 32) {
#pragma unroll
        for (int c = wave; c < ACH; c += 4) {
            const unsigned short* src = A + (size_t)(m0 + c * 16 + srow) * K + k0 + scol;
            async_copy16(src, &Alds[c * 16][0]);
        }
#pragma unroll
        for (int c = wave; c < BCH; c += 4) {
            const unsigned short* src = W + (size_t)(n0 + c * 16 + srow) * K + k0 + scol;
            async_copy16(src, &Blds[c * 16][0]);
        }
        __syncthreads();

        bf16x8 af[FM], bfr[FN];
#pragma unroll
        for (int fm = 0; fm < FM; ++fm)
            af[fm] = *(const bf16x8*)&Alds[wr * (BMT / 2) + fm * 16 + lrow][lk16];
#pragma unroll
        for (int fn = 0; fn < FN; ++fn)
            bfr[fn] = *(const bf16x8*)&Blds[wc * (BNT / 2) + fn * 16 + lrow][lk16];
#pragma unroll
        for (int fm = 0; fm < FM; ++fm)
#pragma unroll
            for (int fn = 0; fn < FN; ++fn)
                acc[fm][fn] = __builtin_amdgcn_mfma_f32_16x16x32_bf16(
                    af[fm], bfr[fn], acc[fm][fn], 0, 0, 0);
        __syncthreads();
    }

    const int lq = lane >> 4;
#pragma unroll
    for (int fm = 0; fm < FM; ++fm) {
#pragma unroll
        for (int fn = 0; fn < FN; ++fn) {
#pragma unroll
            for (int r = 0; r < 4; ++r) {
                const int m = m0 + wr * (BMT / 2) + fm * 16 + lq * 4 + r;
                const int n = n0 + wc * (BNT / 2) + fn * 16 + lrow;
                C[(size_t)m * N + n] = acc[fm][fn][r];
            }
        }
    }
}

// ---------------- K3: split-K bf16 MFMA, N=96 ----------------
__global__ __launch_bounds__(256) void gemm_bf16_k3(
    const unsigned short* __restrict__ A,
    const unsigned short* __restrict__ W,
    float* __restrict__ P)
{
    __shared__ unsigned short Alds[128][32];
    __shared__ unsigned short Blds[96][32];

    const int tid  = threadIdx.x;
    const int lane = tid & 63;
    const int wave = tid >> 6;
    const int wr = wave >> 1, wc = wave & 1;
    const int ks = blockIdx.x;
    const int m0 = blockIdx.y * 128;
    const int kbase = ks * 128;

    const int srow = lane >> 2;
    const int scol = (lane & 3) * 8;
    const int lrow = lane & 15;
    const int lk16 = (lane >> 4) * 8;

    f32x4 acc[4][3];
#pragma unroll
    for (int i = 0; i < 4; ++i)
#pragma unroll
        for (int j = 0; j < 3; ++j) acc[i][j] = (f32x4){0.f, 0.f, 0.f, 0.f};

    for (int kk = 0; kk < 4; ++kk) {
        const int k0 = kbase + kk * 32;
#pragma unroll
        for (int c = wave; c < 8; c += 4)
            async_copy16(A + (size_t)(m0 + c * 16 + srow) * 2048 + k0 + scol, &Alds[c * 16][0]);
#pragma unroll
        for (int c = wave; c < 6; c += 4)
            async_copy16(W + (size_t)(c * 16 + srow) * 2048 + k0 + scol, &Blds[c * 16][0]);
        __syncthreads();

        bf16x8 af[4], bfr[3];
#pragma unroll
        for (int fm = 0; fm < 4; ++fm)
            af[fm] = *(const bf16x8*)&Alds[wr * 64 + fm * 16 + lrow][lk16];
#pragma unroll
        for (int fn = 0; fn < 3; ++fn)
            bfr[fn] = *(const bf16x8*)&Blds[wc * 48 + fn * 16 + lrow][lk16];
#pragma unroll
        for (int fm = 0; fm < 4; ++fm)
#pragma unroll
            for (int fn = 0; fn < 3; ++fn)
                acc[fm][fn] = __builtin_amdgcn_mfma_f32_16x16x32_bf16(
                    af[fm], bfr[fn], acc[fm][fn], 0, 0, 0);
        __syncthreads();
    }

    const int lq = lane >> 4;
    float* Pks = P + (size_t)ks * 2048 * 96;
#pragma unroll
    for (int fm = 0; fm < 4; ++fm) {
#pragma unroll
        for (int fn = 0; fn < 3; ++fn) {
#pragma unroll
            for (int r = 0; r < 4; ++r) {
                const int m = m0 + wr * 64 + fm * 16 + lq * 4 + r;
                const int n = wc * 48 + fn * 16 + lrow;
                Pks[(size_t)m * 96 + n] = acc[fm][fn][r];
            }
        }
    }
}

// reduce 16 partials -> proj (2048 x 96), float4-vectorized
__global__ __launch_bounds__(256) void k3_reduce_kernel(
    const float* __restrict__ P, float* __restrict__ proj)
{
    const int i = blockIdx.x * 256 + threadIdx.x;   // 0..49151 (2048*96/4)
    if (i >= 49152) return;
    float4 s = make_float4(0.f, 0.f, 0.f, 0.f);
#pragma unroll
    for (int ks = 0; ks < 16; ++ks) {
        const float4 v = ((const float4*)P)[(size_t)ks * 49152 + i];
        s.x += v.x; s.y += v.y; s.z += v.z; s.w += v.w;
    }
    ((float4*)proj)[i] = s;
}

// ---------------- K4: delta = softplus(proj[:, :64] @ dt_proj_w^T + b) ----------------
__global__ __launch_bounds__(256) void delta_gemm_kernel(
    const float* __restrict__ A,    // proj, lda=96
    const float* __restrict__ W,    // dt_proj_w, ldw=64
    const float* __restrict__ bias, // dt_proj_b
    float* __restrict__ C)          // delta, ldc=2048
{
    __shared__ float As[64][64];
    __shared__ float Bs[64][64];

    const int tid = threadIdx.x;
    const int m0 = blockIdx.y * 64;
    const int n0 = blockIdx.x * 64;

    {
        const int k4 = tid & 15;
        const int r0 = tid >> 4;      // 0..15
#pragma unroll
        for (int p = 0; p < 4; ++p) {
            const int row = p * 16 + r0;
            const int sw  = k4 ^ (row & 7) ^ (row >> 3);
            *(float4*)&As[row][sw * 4] =
                *(const float4*)(A + (size_t)(m0 + row) * 96 + k4 * 4);
            *(float4*)&Bs[row][sw * 4] =
                *(const float4*)(W + (size_t)(n0 + row) * 64 + k4 * 4);
        }
    }
    __syncthreads();

    const int tx = tid & 15;     // n-group (4 cols)
    const int ty = tid >> 4;     // m-group (4 rows)

    float acc[4][4];
#pragma unroll
    for (int i = 0; i < 4; ++i)
#pragma unroll
        for (int j = 0; j < 4; ++j) acc[i][j] = 0.f;

#pragma unroll 4
    for (int c = 0; c < 16; ++c) {   // 16 chunks of 4 k
        float4 a[4], b[4];
#pragma unroll
        for (int i = 0; i < 4; ++i) {
            const int r = ty * 4 + i;
            a[i] = *(const float4*)&As[r][(c ^ (r & 7) ^ (r >> 3)) * 4];
        }
#pragma unroll
        for (int j = 0; j < 4; ++j) {
            const int r = tx * 4 + j;
            b[j] = *(const float4*)&Bs[r][(c ^ (r & 7) ^ (r >> 3)) * 4];
        }
#pragma unroll
        for (int i = 0; i < 4; ++i)
#pragma unroll
            for (int j = 0; j < 4; ++j) {
                acc[i][j] = fmaf(a[i].x, b[j].x, acc[i][j]);
                acc[i][j] = fmaf(a[i].y, b[j].y, acc[i][j]);
                acc[i][j] = fmaf(a[i].z, b[j].z, acc[i][j]);
                acc[i][j] = fmaf(a[i].w, b[j].w, acc[i][j]);
            }
    }

    const float4 bv = *(const float4*)(bias + n0 + tx * 4);
#pragma unroll
    for (int i = 0; i < 4; ++i) {
        const int m = m0 + ty * 4 + i;
        float v[4];
        v[0] = acc[i][0] + bv.x; v[1] = acc[i][1] + bv.y;
        v[2] = acc[i][2] + bv.z; v[3] = acc[i][3] + bv.w;
        float4 o;
        o.x = (v[0] > 20.f) ? v[0] : __logf(1.f + __expf(v[0]));
        o.y = (v[1] > 20.f) ? v[1] : __logf(1.f + __expf(v[1]));
        o.z = (v[2] > 20.f) ? v[2] : __logf(1.f + __expf(v[2]));
        o.w = (v[3] > 20.f) ? v[3] : __logf(1.f + __expf(v[3]));
        *(float4*)(C + (size_t)m * 2048 + n0 + tx * 4) = o;
    }
}

// causal depthwise conv (width 4) + bias + SiLU; writes fp32 + bf16
__global__ __launch_bounds__(256) void conv_silu_kernel(
    const float* __restrict__ xz, const float* __restrict__ cw,
    const float* __restrict__ cb, float* __restrict__ xs,
    unsigned short* __restrict__ xs_bf)
{
    const int idx = blockIdx.x * 256 + threadIdx.x;
    if (idx >= 2 * 1024 * 2048) return;
    const int d = idx & 2047;
    const int t = (idx >> 11) & 1023;
    const int b = idx >> 21;

    const float* col = xz + (size_t)b * 1024 * 4096 + d;
    const float4 w = *(const float4*)(cw + d * 4);
    float acc = cb[d];
    const int tb = t - 3;
    const float s0 = (tb + 0 >= 0) ? col[(size_t)(tb + 0) * 4096] : 0.f;
    const float s1 = (tb + 1 >= 0) ? col[(size_t)(tb + 1) * 4096] : 0.f;
    const float s2 = (tb + 2 >= 0) ? col[(size_t)(tb + 2) * 4096] : 0.f;
    const float s3 = col[(size_t)t * 4096];
    acc += w.x * s0 + w.y * s1 + w.z * s2 + w.w * s3;
    const float sig = 1.f / (1.f + __expf(-acc));
    const float val = acc * sig;
    xs[idx] = val;
    xs_bf[idx] = f2bf(val);
}

// ---------------- chunked selective scan (r0 structure, strength-reduced) ----
// n=16 per thread, 1024 blocks (d = db*256+tid). Inner step uses
//   a = exp2(dt*A*log2e);  u = invA[n]*B[t][n]*xs;  h = fma(a, h+u, -u)
// == a*h + (a-1)/A * B*xs exactly; the |dA|<0.01 guard branch is dropped
// (fp32 cancellation error <= ~1e-6, three orders below absmax tolerance).
template <int PHASE>
__global__ __launch_bounds__(256) void scan_phase_kernel(
    const float* __restrict__ delta, const float* __restrict__ xs,
    const float* __restrict__ xz, const float* __restrict__ proj,
    const float* __restrict__ A_log, const float* __restrict__ Dp,
    float* __restrict__ Pbuf, float* __restrict__ hcbuf,
    unsigned short* __restrict__ ybf)
{
    const int tid = threadIdx.x;
    const int cb = blockIdx.x;
    const int chunk = cb & 63;
    const int db = (cb >> 6) & 7;
    const int b = cb >> 9;
    const int d = db * 256 + tid;
    const int t0 = chunk * 16;

    __shared__ float Bs[16][16];
    __shared__ float Cs[16][16];
    {
        const int tt = tid >> 4, nn = tid & 15;
        Bs[tt][nn] = proj[((size_t)b * 1024 + t0 + tt) * 96 + 64 + nn];
        if (PHASE == 3)
            Cs[tt][nn] = proj[((size_t)b * 1024 + t0 + tt) * 96 + 80 + nn];
    }
    __syncthreads();

    // A2 = A * log2e (for exp2); invA = 1/A (true A)
    float A2[16], invA[16], h[16], Pacc[16];
#pragma unroll
    for (int n4 = 0; n4 < 4; ++n4) {
        const float4 al = *(const float4*)(A_log + d * 16 + n4 * 4);
        const float a0 = -__expf(al.x);
        const float a1 = -__expf(al.y);
        const float a2 = -__expf(al.z);
        const float a3 = -__expf(al.w);
        A2[n4 * 4 + 0] = a0 * 1.44269504088896f; invA[n4 * 4 + 0] = 1.f / a0;
        A2[n4 * 4 + 1] = a1 * 1.44269504088896f; invA[n4 * 4 + 1] = 1.f / a1;
        A2[n4 * 4 + 2] = a2 * 1.44269504088896f; invA[n4 * 4 + 2] = 1.f / a2;
        A2[n4 * 4 + 3] = a3 * 1.44269504088896f; invA[n4 * 4 + 3] = 1.f / a3;
    }
#pragma unroll
    for (int n = 0; n < 16; ++n) Pacc[n] = 1.f;
    if (PHASE == 1) {
#pragma unroll
        for (int n = 0; n < 16; ++n) h[n] = 0.f;
    } else {
#pragma unroll
        for (int n = 0; n < 16; ++n)
            h[n] = hcbuf[(((size_t)b * 64 + chunk) * 16 + n) * 2048 + d];
    }
    const float Dd = Dp[d];

    const float* dptr = delta + ((size_t)b * 1024 + t0) * 2048 + d;
    const float* xptr = xs + ((size_t)b * 1024 + t0) * 2048 + d;
    const float* zptr = xz + ((size_t)b * 1024 + t0) * 4096 + 2048 + d;
    unsigned short* yptr = ybf + ((size_t)b * 1024 + t0) * 2048 + d;

#pragma unroll 4
    for (int t = 0; t < 16; ++t) {
        const float dt_v = dptr[(size_t)t * 2048];
        const float xs_v = xptr[(size_t)t * 2048];
        float ysum = 0.f;
#pragma unroll
        for (int n = 0; n < 16; ++n) {
            const float a = __builtin_amdgcn_exp2f(dt_v * A2[n]);
            const float u = invA[n] * Bs[t][n] * xs_v;
            h[n] = fmaf(a, h[n] + u, -u);
            if (PHASE == 1) Pacc[n] *= a;
            else ysum = fmaf(h[n], Cs[t][n], ysum);
        }
        if (PHASE == 3) {
            const float z_v = zptr[(size_t)t * 4096];
            const float yv = ysum + Dd * xs_v;
            const float sig = 1.f / (1.f + __expf(-z_v));
            yptr[(size_t)t * 2048] = f2bf(yv * (z_v * sig));
        }
    }
    if (PHASE == 1) {
#pragma unroll
        for (int n = 0; n < 16; ++n) {
            const size_t idx = (((size_t)b * 64 + chunk) * 16 + n) * 2048 + d;
            Pbuf[idx] = Pacc[n];
            hcbuf[idx] = h[n];
        }
    }
}

__global__ __launch_bounds__(256) void scan_combine_kernel(
    const float* __restrict__ Pbuf, float* __restrict__ hcbuf)
{
    const int gid = blockIdx.x * 256 + threadIdx.x;
    const int d = gid & 2047;
    const int n = (gid >> 11) & 15;
    const int b = gid >> 15;

    const size_t base = (((size_t)b * 64) * 16 + n) * 2048 + d;
    const size_t cstride = (size_t)16 * 2048;

    float H = 0.f;
    float P = Pbuf[base], hl = hcbuf[base];
    for (int c = 0; c < 64; ++c) {
        float nP = 0.f, nhl = 0.f;
        if (c + 1 < 64) {
            nP  = Pbuf[base + (size_t)(c + 1) * cstride];
            nhl = hcbuf[base + (size_t)(c + 1) * cstride];
        }
        hcbuf[base + (size_t)c * cstride] = H;
        H = fmaf(P, H, hl);
        P = nP; hl = nhl;
    }
}

extern "C" void kernel_launch(void* const* d_in, const int* in_sizes, int n_in,
                              void* d_out, int out_size, void* d_ws, size_t ws_size,
                              hipStream_t stream) {
    const float* x         = (const float*)d_in[0];
    const float* in_proj_w = (const float*)d_in[1];
    const float* conv_w    = (const float*)d_in[2];
    const float* conv_b    = (const float*)d_in[3];
    const float* x_proj_w  = (const float*)d_in[4];
    const float* dt_proj_w = (const float*)d_in[5];
    const float* dt_proj_b = (const float*)d_in[6];
    const float* A_log     = (const float*)d_in[7];
    const float* Dp        = (const float*)d_in[8];
    const float* out_proj_w= (const float*)d_in[9];
    float* out = (float*)d_out;

    float* ws    = (float*)d_ws;
    float* xz    = ws;                              // (2048,4096) 32 MB
    float* xs    = ws + 8388608;                    // (2048,2048) 16 MB
    float* delta = ws + 12582912;                   // (2048,2048) 16 MB
    float* Pbuf  = ws + 16777216;                   // 16 MB
    float* proj  = ws + 20971520;                   // (2048,96)
    float* hcbuf = ws + 21168128;                   // 16 MB

    // bf16 staging / partial buffers in dead regions:
    unsigned short* x_bf   = (unsigned short*)(ws + 12582912); // delta region (dead until K4)
    unsigned short* w1_bf  = (unsigned short*)(ws + 13631488); // delta region, ends at 15728640
    float*          part3  = ws + 12582912;                    // [16][2048][96] fp32, K3 partials (after K1)
    unsigned short* xw_bf  = (unsigned short*)(ws + 15728640); // 96x2048 bf16
    unsigned short* xs_bf  = (unsigned short*)(ws + 16777216); // Pbuf region (dead until scan ph1)
    unsigned short* ybf    = (unsigned short*)(ws + 16777216); // over Pbuf (dead after combine)
    unsigned short* wout_bf= (unsigned short*)ws;              // xz region (dead after phase 3)

    // conversions
    f32_to_bf16_kernel<<<2048, 256, 0, stream>>>(x, x_bf, 524288);
    f32_to_bf16_kernel<<<4096, 256, 0, stream>>>(in_proj_w, w1_bf, 1048576);
    f32_to_bf16_kernel<<<192, 256, 0, stream>>>(x_proj_w, xw_bf, 49152);

    // K1: xz = x @ in_proj_w^T   (M=2048, N=4096, K=1024) — bf16 MFMA
    gemm_bf16_nt<128, 128><<<dim3(4096 / 128, 2048 / 128), 256, 0, stream>>>(
        x_bf, w1_bf, xz, 2048, 4096, 1024);

    // K2: causal conv + bias + silu -> xs (fp32) + xs_bf (bf16)
    conv_silu_kernel<<<(2 * 1024 * 2048) / 256, 256, 0, stream>>>(xz, conv_w, conv_b, xs, xs_bf);

    // K3: split-K bf16 MFMA -> partials -> reduce into proj
    gemm_bf16_k3<<<dim3(16, 16), 256, 0, stream>>>(xs_bf, xw_bf, part3);
    k3_reduce_kernel<<<192, 256, 0, stream>>>(part3, proj);

    // K4: delta = softplus(proj[:, :64] @ dt_proj_w^T + dt_proj_b) — fp32, 64x64 tiles
    delta_gemm_kernel<<<dim3(2048 / 64, 2048 / 64), 256, 0, stream>>>(
        proj, dt_proj_w, dt_proj_b, delta);

    // K5: chunked selective scan -> ybf (bf16); 1024 blocks, n=16/thread (r0 structure)
    scan_phase_kernel<1><<<1024, 256, 0, stream>>>(
        delta, xs, xz, proj, A_log, Dp, Pbuf, hcbuf, ybf);
    scan_combine_kernel<<<256, 256, 0, stream>>>(Pbuf, hcbuf);
    scan_phase_kernel<3><<<1024, 256, 0, stream>>>(
        delta, xs, xz, proj, A_log, Dp, Pbuf, hcbuf, ybf);

    // convert out_proj_w into xz region (xz dead after phase 3)
    f32_to_bf16_kernel<<<2048, 256, 0, stream>>>(out_proj_w, wout_bf, 524288);

    // K7: out = y @ out_proj_w^T  (M=2048, N=1024, K=2048) — bf16 MFMA
    gemm_bf16_nt<64, 128><<<dim3(1024 / 128, 2048 / 64), 256, 0, stream>>>(
        ybf, wout_bf, out, 2048, 1024, 2048);
}

// Round 7
// 168.023 us; speedup vs baseline: 3.0178x; 1.0275x over previous
//
#include <hip/hip_runtime.h>
#include <hip/hip_bf16.h>
#include <math.h>

typedef __attribute__((ext_vector_type(8))) short bf16x8;
typedef __attribute__((ext_vector_type(4))) float f32x4;

__device__ __forceinline__ unsigned short f2bf(float f) {
    unsigned int u = __float_as_uint(f);
    u = (u + 0x7fff + ((u >> 16) & 1)) >> 16;   // RNE
    return (unsigned short)u;
}

__device__ __forceinline__ float bf2f(unsigned short u) {
    return __uint_as_float(((unsigned int)u) << 16);
}

__device__ __forceinline__ void async_copy16(const unsigned short* g, unsigned short* l) {
    __builtin_amdgcn_global_load_lds(
        (const __attribute__((address_space(1))) unsigned int*)g,
        (__attribute__((address_space(3))) unsigned int*)l,
        16, 0, 0);
}

// ---------------- fp32 -> bf16 conversion (vectorized) ----------------
__global__ __launch_bounds__(256) void f32_to_bf16_kernel(
    const float* __restrict__ in, unsigned short* __restrict__ out, int n4)
{
    const int i = blockIdx.x * 256 + threadIdx.x;
    if (i >= n4) return;
    const float4 v = ((const float4*)in)[i];
    ushort4 o;
    o.x = f2bf(v.x); o.y = f2bf(v.y); o.z = f2bf(v.z); o.w = f2bf(v.w);
    ((ushort4*)out)[i] = o;
}

// fp32 -> split bf16 (hi + lo residual), for ~fp32-accurate MFMA
__global__ __launch_bounds__(256) void f32_to_bf16x2_kernel(
    const float* __restrict__ in, unsigned short* __restrict__ hi,
    unsigned short* __restrict__ lo, int n4)
{
    const int i = blockIdx.x * 256 + threadIdx.x;
    if (i >= n4) return;
    const float4 v = ((const float4*)in)[i];
    ushort4 h, l;
    h.x = f2bf(v.x); l.x = f2bf(v.x - bf2f(h.x));
    h.y = f2bf(v.y); l.y = f2bf(v.y - bf2f(h.y));
    h.z = f2bf(v.z); l.z = f2bf(v.z - bf2f(h.z));
    h.w = f2bf(v.w); l.w = f2bf(v.w - bf2f(h.w));
    ((ushort4*)hi)[i] = h;
    ((ushort4*)lo)[i] = l;
}

// ---------------- bf16 MFMA GEMM: C[m][n] = sum_k A[m][k] * W[n][k] ----------------
template <int BMT, int BNT>
__global__ __launch_bounds__(256) void gemm_bf16_nt(
    const unsigned short* __restrict__ A,
    const unsigned short* __restrict__ W,
    float* __restrict__ C, int M, int N, int K)
{
    constexpr int FM = BMT / 32;
    constexpr int FN = BNT / 32;
    constexpr int ACH = BMT / 16;
    constexpr int BCH = BNT / 16;

    __shared__ unsigned short Alds[BMT][32];
    __shared__ unsigned short Blds[BNT][32];

    const int tid  = threadIdx.x;
    const int lane = tid & 63;
    const int wave = tid >> 6;
    const int wr = wave >> 1, wc = wave & 1;
    const int m0 = blockIdx.y * BMT;
    const int n0 = blockIdx.x * BNT;

    const int srow = lane >> 2;
    const int scol = (lane & 3) * 8;

    f32x4 acc[FM][FN];
#pragma unroll
    for (int i = 0; i < FM; ++i)
#pragma unroll
        for (int j = 0; j < FN; ++j) acc[i][j] = (f32x4){0.f, 0.f, 0.f, 0.f};

    const int lrow = lane & 15;
    const int lk16 = (lane >> 4) * 8;

    for (int k0 = 0; k0 < K; k0 += 32) {
#pragma unroll
        for (int c = wave; c < ACH; c += 4) {
            const unsigned short* src = A + (size_t)(m0 + c * 16 + srow) * K + k0 + scol;
            async_copy16(src, &Alds[c * 16][0]);
        }
#pragma unroll
        for (int c = wave; c < BCH; c += 4) {
            const unsigned short* src = W + (size_t)(n0 + c * 16 + srow) * K + k0 + scol;
            async_copy16(src, &Blds[c * 16][0]);
        }
        __syncthreads();

        bf16x8 af[FM], bfr[FN];
#pragma unroll
        for (int fm = 0; fm < FM; ++fm)
            af[fm] = *(const bf16x8*)&Alds[wr * (BMT / 2) + fm * 16 + lrow][lk16];
#pragma unroll
        for (int fn = 0; fn < FN; ++fn)
            bfr[fn] = *(const bf16x8*)&Blds[wc * (BNT / 2) + fn * 16 + lrow][lk16];
#pragma unroll
        for (int fm = 0; fm < FM; ++fm)
#pragma unroll
            for (int fn = 0; fn < FN; ++fn)
                acc[fm][fn] = __builtin_amdgcn_mfma_f32_16x16x32_bf16(
                    af[fm], bfr[fn], acc[fm][fn], 0, 0, 0);
        __syncthreads();
    }

    const int lq = lane >> 4;
#pragma unroll
    for (int fm = 0; fm < FM; ++fm) {
#pragma unroll
        for (int fn = 0; fn < FN; ++fn) {
#pragma unroll
            for (int r = 0; r < 4; ++r) {
                const int m = m0 + wr * (BMT / 2) + fm * 16 + lq * 4 + r;
                const int n = n0 + wc * (BNT / 2) + fn * 16 + lrow;
                C[(size_t)m * N + n] = acc[fm][fn][r];
            }
        }
    }
}

// ---------------- K3: split-K bf16 MFMA, N=96 ----------------
__global__ __launch_bounds__(256) void gemm_bf16_k3(
    const unsigned short* __restrict__ A,
    const unsigned short* __restrict__ W,
    float* __restrict__ P)
{
    __shared__ unsigned short Alds[128][32];
    __shared__ unsigned short Blds[96][32];

    const int tid  = threadIdx.x;
    const int lane = tid & 63;
    const int wave = tid >> 6;
    const int wr = wave >> 1, wc = wave & 1;
    const int ks = blockIdx.x;
    const int m0 = blockIdx.y * 128;
    const int kbase = ks * 128;

    const int srow = lane >> 2;
    const int scol = (lane & 3) * 8;
    const int lrow = lane & 15;
    const int lk16 = (lane >> 4) * 8;

    f32x4 acc[4][3];
#pragma unroll
    for (int i = 0; i < 4; ++i)
#pragma unroll
        for (int j = 0; j < 3; ++j) acc[i][j] = (f32x4){0.f, 0.f, 0.f, 0.f};

    for (int kk = 0; kk < 4; ++kk) {
        const int k0 = kbase + kk * 32;
#pragma unroll
        for (int c = wave; c < 8; c += 4)
            async_copy16(A + (size_t)(m0 + c * 16 + srow) * 2048 + k0 + scol, &Alds[c * 16][0]);
#pragma unroll
        for (int c = wave; c < 6; c += 4)
            async_copy16(W + (size_t)(c * 16 + srow) * 2048 + k0 + scol, &Blds[c * 16][0]);
        __syncthreads();

        bf16x8 af[4], bfr[3];
#pragma unroll
        for (int fm = 0; fm < 4; ++fm)
            af[fm] = *(const bf16x8*)&Alds[wr * 64 + fm * 16 + lrow][lk16];
#pragma unroll
        for (int fn = 0; fn < 3; ++fn)
            bfr[fn] = *(const bf16x8*)&Blds[wc * 48 + fn * 16 + lrow][lk16];
#pragma unroll
        for (int fm = 0; fm < 4; ++fm)
#pragma unroll
            for (int fn = 0; fn < 3; ++fn)
                acc[fm][fn] = __builtin_amdgcn_mfma_f32_16x16x32_bf16(
                    af[fm], bfr[fn], acc[fm][fn], 0, 0, 0);
        __syncthreads();
    }

    const int lq = lane >> 4;
    float* Pks = P + (size_t)ks * 2048 * 96;
#pragma unroll
    for (int fm = 0; fm < 4; ++fm) {
#pragma unroll
        for (int fn = 0; fn < 3; ++fn) {
#pragma unroll
            for (int r = 0; r < 4; ++r) {
                const int m = m0 + wr * 64 + fm * 16 + lq * 4 + r;
                const int n = wc * 48 + fn * 16 + lrow;
                Pks[(size_t)m * 96 + n] = acc[fm][fn][r];
            }
        }
    }
}

// reduce 16 partials -> proj (2048 x 96) + split-bf16 planes of delta_r cols
__global__ __launch_bounds__(256) void k3_reduce_kernel(
    const float* __restrict__ P, float* __restrict__ proj,
    unsigned short* __restrict__ dr_hi, unsigned short* __restrict__ dr_lo)
{
    const int i = blockIdx.x * 256 + threadIdx.x;   // 0..49151 (2048*96/4)
    if (i >= 49152) return;
    float4 s = make_float4(0.f, 0.f, 0.f, 0.f);
#pragma unroll
    for (int ks = 0; ks < 16; ++ks) {
        const float4 v = ((const float4*)P)[(size_t)ks * 49152 + i];
        s.x += v.x; s.y += v.y; s.z += v.z; s.w += v.w;
    }
    ((float4*)proj)[i] = s;

    const int row = i / 24;
    const int c4  = i - row * 24;
    if (c4 < 16) {  // delta_r columns 0..63 -> [2048][64] split-bf16
        ushort4 h, l;
        h.x = f2bf(s.x); l.x = f2bf(s.x - bf2f(h.x));
        h.y = f2bf(s.y); l.y = f2bf(s.y - bf2f(h.y));
        h.z = f2bf(s.z); l.z = f2bf(s.z - bf2f(h.z));
        h.w = f2bf(s.w); l.w = f2bf(s.w - bf2f(h.w));
        ((ushort4*)dr_hi)[row * 16 + c4] = h;
        ((ushort4*)dr_lo)[row * 16 + c4] = l;
    }
}

// ---------------- K4: delta = softplus(delta_r @ dt_proj_w^T + b), split-bf16 MFMA ----
// A = dr_{hi,lo} [2048][64], W = wt_{hi,lo} [2048][64]. Tile 64x128, K=64 (2 steps).
// acc += ahi*bhi + alo*bhi + ahi*blo  (~fp32 accuracy, rel err ~2^-17).
__global__ __launch_bounds__(256) void delta_mfma_kernel(
    const unsigned short* __restrict__ Ahi, const unsigned short* __restrict__ Alo,
    const unsigned short* __restrict__ Whi, const unsigned short* __restrict__ Wlo,
    const float* __restrict__ bias, float* __restrict__ C)
{
    __shared__ unsigned short AhiL[64][32], AloL[64][32];
    __shared__ unsigned short WhiL[128][32], WloL[128][32];

    const int tid  = threadIdx.x;
    const int lane = tid & 63;
    const int wave = tid >> 6;
    const int wr = wave >> 1, wc = wave & 1;
    const int m0 = blockIdx.y * 64;
    const int n0 = blockIdx.x * 128;

    const int srow = lane >> 2;
    const int scol = (lane & 3) * 8;
    const int lrow = lane & 15;
    const int lk16 = (lane >> 4) * 8;

    f32x4 acc[2][4];
#pragma unroll
    for (int i = 0; i < 2; ++i)
#pragma unroll
        for (int j = 0; j < 4; ++j) acc[i][j] = (f32x4){0.f, 0.f, 0.f, 0.f};

#pragma unroll
    for (int ks = 0; ks < 2; ++ks) {
        const int k0 = ks * 32;
#pragma unroll
        for (int c = wave; c < 4; c += 4) {
            async_copy16(Ahi + (size_t)(m0 + c * 16 + srow) * 64 + k0 + scol, &AhiL[c * 16][0]);
            async_copy16(Alo + (size_t)(m0 + c * 16 + srow) * 64 + k0 + scol, &AloL[c * 16][0]);
        }
#pragma unroll
        for (int c = wave; c < 8; c += 4) {
            async_copy16(Whi + (size_t)(n0 + c * 16 + srow) * 64 + k0 + scol, &WhiL[c * 16][0]);
            async_copy16(Wlo + (size_t)(n0 + c * 16 + srow) * 64 + k0 + scol, &WloL[c * 16][0]);
        }
        __syncthreads();

        bf16x8 ah[2], al[2], bh[4], bl[4];
#pragma unroll
        for (int fm = 0; fm < 2; ++fm) {
            ah[fm] = *(const bf16x8*)&AhiL[wr * 32 + fm * 16 + lrow][lk16];
            al[fm] = *(const bf16x8*)&AloL[wr * 32 + fm * 16 + lrow][lk16];
        }
#pragma unroll
        for (int fn = 0; fn < 4; ++fn) {
            bh[fn] = *(const bf16x8*)&WhiL[wc * 64 + fn * 16 + lrow][lk16];
            bl[fn] = *(const bf16x8*)&WloL[wc * 64 + fn * 16 + lrow][lk16];
        }
#pragma unroll
        for (int fm = 0; fm < 2; ++fm)
#pragma unroll
            for (int fn = 0; fn < 4; ++fn) {
                acc[fm][fn] = __builtin_amdgcn_mfma_f32_16x16x32_bf16(
                    ah[fm], bh[fn], acc[fm][fn], 0, 0, 0);
                acc[fm][fn] = __builtin_amdgcn_mfma_f32_16x16x32_bf16(
                    al[fm], bh[fn], acc[fm][fn], 0, 0, 0);
                acc[fm][fn] = __builtin_amdgcn_mfma_f32_16x16x32_bf16(
                    ah[fm], bl[fn], acc[fm][fn], 0, 0, 0);
            }
        __syncthreads();
    }

    const int lq = lane >> 4;
#pragma unroll
    for (int fm = 0; fm < 2; ++fm) {
#pragma unroll
        for (int fn = 0; fn < 4; ++fn) {
#pragma unroll
            for (int r = 0; r < 4; ++r) {
                const int m = m0 + wr * 32 + fm * 16 + lq * 4 + r;
                const int n = n0 + wc * 64 + fn * 16 + lrow;
                float v = acc[fm][fn][r] + bias[n];
                v = (v > 20.f) ? v : __logf(1.f + __expf(v));
                C[(size_t)m * 2048 + n] = v;
            }
        }
    }
}

// causal depthwise conv (width 4) + bias + SiLU; writes fp32 + bf16
__global__ __launch_bounds__(256) void conv_silu_kernel(
    const float* __restrict__ xz, const float* __restrict__ cw,
    const float* __restrict__ cb, float* __restrict__ xs,
    unsigned short* __restrict__ xs_bf)
{
    const int idx = blockIdx.x * 256 + threadIdx.x;
    if (idx >= 2 * 1024 * 2048) return;
    const int d = idx & 2047;
    const int t = (idx >> 11) & 1023;
    const int b = idx >> 21;

    const float* col = xz + (size_t)b * 1024 * 4096 + d;
    const float4 w = *(const float4*)(cw + d * 4);
    float acc = cb[d];
    const int tb = t - 3;
    const float s0 = (tb + 0 >= 0) ? col[(size_t)(tb + 0) * 4096] : 0.f;
    const float s1 = (tb + 1 >= 0) ? col[(size_t)(tb + 1) * 4096] : 0.f;
    const float s2 = (tb + 2 >= 0) ? col[(size_t)(tb + 2) * 4096] : 0.f;
    const float s3 = col[(size_t)t * 4096];
    acc += w.x * s0 + w.y * s1 + w.z * s2 + w.w * s3;
    const float sig = 1.f / (1.f + __expf(-acc));
    const float val = acc * sig;
    xs[idx] = val;
    xs_bf[idx] = f2bf(val);
}

// ---------------- chunked selective scan (r6 structure + 2-deep scalar pipeline) ----
// n=16/thread, 1024 blocks. dt/xs(/z) prefetched 2 t-steps ahead via named rotating
// scalars (NO local arrays -> no scratch; rule #20). Phase 1: Pacc via dtsum
// (prod of exp2 == exp2 of sum), 16 muls/t removed from inner loop.
template <int PHASE>
__global__ __launch_bounds__(256) void scan_phase_kernel(
    const float* __restrict__ delta, const float* __restrict__ xs,
    const float* __restrict__ xz, const float* __restrict__ proj,
    const float* __restrict__ A_log, const float* __restrict__ Dp,
    float* __restrict__ Pbuf, float* __restrict__ hcbuf,
    unsigned short* __restrict__ ybf)
{
    const int tid = threadIdx.x;
    const int cb = blockIdx.x;
    const int chunk = cb & 63;
    const int db = (cb >> 6) & 7;
    const int b = cb >> 9;
    const int d = db * 256 + tid;
    const int t0 = chunk * 16;

    __shared__ float Bs[16][16];
    __shared__ float Cs[16][16];
    {
        const int tt = tid >> 4, nn = tid & 15;
        Bs[tt][nn] = proj[((size_t)b * 1024 + t0 + tt) * 96 + 64 + nn];
        if (PHASE == 3)
            Cs[tt][nn] = proj[((size_t)b * 1024 + t0 + tt) * 96 + 80 + nn];
    }
    __syncthreads();

    // A2 = A * log2e (for exp2); invA = 1/A (true A)
    float A2[16], invA[16], h[16];
#pragma unroll
    for (int n4 = 0; n4 < 4; ++n4) {
        const float4 al = *(const float4*)(A_log + d * 16 + n4 * 4);
        const float a0 = -__expf(al.x);
        const float a1 = -__expf(al.y);
        const float a2 = -__expf(al.z);
        const float a3 = -__expf(al.w);
        A2[n4 * 4 + 0] = a0 * 1.44269504088896f; invA[n4 * 4 + 0] = 1.f / a0;
        A2[n4 * 4 + 1] = a1 * 1.44269504088896f; invA[n4 * 4 + 1] = 1.f / a1;
        A2[n4 * 4 + 2] = a2 * 1.44269504088896f; invA[n4 * 4 + 2] = 1.f / a2;
        A2[n4 * 4 + 3] = a3 * 1.44269504088896f; invA[n4 * 4 + 3] = 1.f / a3;
    }
    if (PHASE == 1) {
#pragma unroll
        for (int n = 0; n < 16; ++n) h[n] = 0.f;
    } else {
#pragma unroll
        for (int n = 0; n < 16; ++n)
            h[n] = hcbuf[(((size_t)b * 64 + chunk) * 16 + n) * 2048 + d];
    }
    const float Dd = Dp[d];

    const float* dptr = delta + ((size_t)b * 1024 + t0) * 2048 + d;
    const float* xptr = xs + ((size_t)b * 1024 + t0) * 2048 + d;
    const float* zptr = xz + ((size_t)b * 1024 + t0) * 4096 + 2048 + d;
    unsigned short* yptr = ybf + ((size_t)b * 1024 + t0) * 2048 + d;

    float dtsum = 0.f;

    // 2-deep prefetch pipeline (named scalars only)
    float dc = dptr[0], xc = xptr[0];
    float dn1 = dptr[2048], xn1 = xptr[2048];
    float zc = 0.f, zn1 = 0.f;
    if (PHASE == 3) { zc = zptr[0]; zn1 = zptr[4096]; }

#pragma unroll
    for (int t = 0; t < 16; ++t) {
        float dn2 = 0.f, xn2 = 0.f, zn2 = 0.f;
        if (t < 14) {
            dn2 = dptr[(size_t)(t + 2) * 2048];
            xn2 = xptr[(size_t)(t + 2) * 2048];
            if (PHASE == 3) zn2 = zptr[(size_t)(t + 2) * 4096];
        }
        const float dt_v = dc;
        const float xs_v = xc;
        if (PHASE == 1) dtsum += dt_v;
        float ysum = 0.f;
#pragma unroll
        for (int n = 0; n < 16; ++n) {
            const float a = __builtin_amdgcn_exp2f(dt_v * A2[n]);
            const float u = invA[n] * Bs[t][n] * xs_v;
            h[n] = fmaf(a, h[n] + u, -u);
            if (PHASE == 3) ysum = fmaf(h[n], Cs[t][n], ysum);
        }
        if (PHASE == 3) {
            const float z_v = zc;
            const float yv = ysum + Dd * xs_v;
            const float sig = 1.f / (1.f + __expf(-z_v));
            yptr[(size_t)t * 2048] = f2bf(yv * (z_v * sig));
        }
        dc = dn1; xc = xn1; zc = zn1;
        dn1 = dn2; xn1 = xn2; zn1 = zn2;
    }
    if (PHASE == 1) {
#pragma unroll
        for (int n = 0; n < 16; ++n) {
            const size_t idx = (((size_t)b * 64 + chunk) * 16 + n) * 2048 + d;
            Pbuf[idx] = __builtin_amdgcn_exp2f(dtsum * A2[n]);
            hcbuf[idx] = h[n];
        }
    }
}

__global__ __launch_bounds__(256) void scan_combine_kernel(
    const float* __restrict__ Pbuf, float* __restrict__ hcbuf)
{
    const int gid = blockIdx.x * 256 + threadIdx.x;
    const int d = gid & 2047;
    const int n = (gid >> 11) & 15;
    const int b = gid >> 15;

    const size_t base = (((size_t)b * 64) * 16 + n) * 2048 + d;
    const size_t cstride = (size_t)16 * 2048;

    float H = 0.f;
    float P = Pbuf[base], hl = hcbuf[base];
    for (int c = 0; c < 64; ++c) {
        float nP = 0.f, nhl = 0.f;
        if (c + 1 < 64) {
            nP  = Pbuf[base + (size_t)(c + 1) * cstride];
            nhl = hcbuf[base + (size_t)(c + 1) * cstride];
        }
        hcbuf[base + (size_t)c * cstride] = H;
        H = fmaf(P, H, hl);
        P = nP; hl = nhl;
    }
}

extern "C" void kernel_launch(void* const* d_in, const int* in_sizes, int n_in,
                              void* d_out, int out_size, void* d_ws, size_t ws_size,
                              hipStream_t stream) {
    const float* x         = (const float*)d_in[0];
    const float* in_proj_w = (const float*)d_in[1];
    const float* conv_w    = (const float*)d_in[2];
    const float* conv_b    = (const float*)d_in[3];
    const float* x_proj_w  = (const float*)d_in[4];
    const float* dt_proj_w = (const float*)d_in[5];
    const float* dt_proj_b = (const float*)d_in[6];
    const float* A_log     = (const float*)d_in[7];
    const float* Dp        = (const float*)d_in[8];
    const float* out_proj_w= (const float*)d_in[9];
    float* out = (float*)d_out;

    float* ws    = (float*)d_ws;
    float* xz    = ws;                              // (2048,4096) 32 MB
    float* xs    = ws + 8388608;                    // (2048,2048) 16 MB
    float* delta = ws + 12582912;                   // (2048,2048) 16 MB
    float* Pbuf  = ws + 16777216;                   // 16 MB
    float* proj  = ws + 20971520;                   // (2048,96)
    float* hcbuf = ws + 21168128;                   // 16 MB, ends 25362432

    // bf16 staging / partial buffers in dead regions:
    unsigned short* x_bf   = (unsigned short*)(ws + 12582912); // delta region (dead until K4)
    unsigned short* w1_bf  = (unsigned short*)(ws + 13631488); // delta region, ends at 15728640
    float*          part3  = ws + 12582912;                    // [16][2048][96] fp32, K3 partials (after K1)
    unsigned short* xw_bf  = (unsigned short*)(ws + 15728640); // 96x2048 bf16
    unsigned short* xs_bf  = (unsigned short*)(ws + 16777216); // Pbuf region (dead until scan ph1)
    unsigned short* ybf    = (unsigned short*)(ws + 16777216); // over Pbuf (dead after combine)
    unsigned short* wout_bf= (unsigned short*)ws;              // xz region (dead after phase 3)
    // split-bf16 planes for K4 (fresh region past hcbuf; each 2048x64 ushorts)
    unsigned short* dr_hi  = (unsigned short*)(ws + 25362432);
    unsigned short* dr_lo  = (unsigned short*)(ws + 25427968);
    unsigned short* wt_hi  = (unsigned short*)(ws + 25493504);
    unsigned short* wt_lo  = (unsigned short*)(ws + 25559040); // ends 25624576 (102.5 MB)

    // conversions
    f32_to_bf16_kernel<<<2048, 256, 0, stream>>>(x, x_bf, 524288);
    f32_to_bf16_kernel<<<4096, 256, 0, stream>>>(in_proj_w, w1_bf, 1048576);
    f32_to_bf16_kernel<<<192, 256, 0, stream>>>(x_proj_w, xw_bf, 49152);
    f32_to_bf16x2_kernel<<<128, 256, 0, stream>>>(dt_proj_w, wt_hi, wt_lo, 32768);

    // K1: xz = x @ in_proj_w^T   (M=2048, N=4096, K=1024) — bf16 MFMA
    gemm_bf16_nt<128, 128><<<dim3(4096 / 128, 2048 / 128), 256, 0, stream>>>(
        x_bf, w1_bf, xz, 2048, 4096, 1024);

    // K2: causal conv + bias + silu -> xs (fp32) + xs_bf (bf16)
    conv_silu_kernel<<<(2 * 1024 * 2048) / 256, 256, 0, stream>>>(xz, conv_w, conv_b, xs, xs_bf);

    // K3: split-K bf16 MFMA -> partials -> reduce into proj (+ split-bf16 delta_r)
    gemm_bf16_k3<<<dim3(16, 16), 256, 0, stream>>>(xs_bf, xw_bf, part3);
    k3_reduce_kernel<<<192, 256, 0, stream>>>(part3, proj, dr_hi, dr_lo);

    // K4: delta = softplus(delta_r @ dt_proj_w^T + b) — split-bf16 MFMA
    delta_mfma_kernel<<<dim3(2048 / 128, 2048 / 64), 256, 0, stream>>>(
        dr_hi, dr_lo, wt_hi, wt_lo, dt_proj_b, delta);

    // K5: chunked selective scan -> ybf (bf16); 1024 blocks, n=16/thread
    scan_phase_kernel<1><<<1024, 256, 0, stream>>>(
        delta, xs, xz, proj, A_log, Dp, Pbuf, hcbuf, ybf);
    scan_combine_kernel<<<256, 256, 0, stream>>>(Pbuf, hcbuf);
    scan_phase_kernel<3><<<1024, 256, 0, stream>>>(
        delta, xs, xz, proj, A_log, Dp, Pbuf, hcbuf, ybf);

    // convert out_proj_w into xz region (xz dead after phase 3)
    f32_to_bf16_kernel<<<2048, 256, 0, stream>>>(out_proj_w, wout_bf, 524288);

    // K7: out = y @ out_proj_w^T  (M=2048, N=1024, K=2048) — bf16 MFMA
    gemm_bf16_nt<64, 128><<<dim3(1024 / 128, 2048 / 64), 256, 0, stream>>>(
        ybf, wout_bf, out, 2048, 1024, 2048);
}